// Round 4
// baseline (259.283 us; speedup 1.0000x reference)
//
#include <hip/hip_runtime.h>

// Trilinear resample (identity affine) of (B=4, D=64, H=64, W=64, C=32) fp32.
// Separable: out[m] = in[max(m-1,0)]*(1-f) + in[m]*f, f = frac(m*62/63), per axis.
// v3: same 2x2x2-outputs-per-thread separable scheme as v2 (27 loads / 8 outputs),
// but ALL 27 loads issued up front into distinct registers (no plane serialization).
// v2 post-mortem: VGPR=52 -> compiler batched loads 9-at-a-time with full drains;
// occupancy 31%, ~90 outstanding misses/CU -> latency-bound at ~84us, same as v1.
// v3 allows ~170 VGPR (launch_bounds 256,3): 3 waves/SIMD x 27 loads in flight
// = ~324 outstanding misses/CU, ~3.4x the MLP on 2.4x less traffic than v1.

#define C4 8  // float4 quads per voxel (32 channels)

typedef float f4raw __attribute__((ext_vector_type(4)));

__device__ __forceinline__ void nt_store(float4 v, float4* p) {
    __builtin_nontemporal_store(*reinterpret_cast<f4raw*>(&v),
                                reinterpret_cast<f4raw*>(p));
}

__device__ __forceinline__ float4 f4lerp(float4 a, float wa, float4 b, float wb) {
    float4 r;
    r.x = fmaf(a.x, wa, b.x * wb);
    r.y = fmaf(a.y, wa, b.y * wb);
    r.z = fmaf(a.z, wa, b.z * wb);
    r.w = fmaf(a.w, wa, b.w * wb);
    return r;
}

__global__ __launch_bounds__(256, 3) void trilerp_kernel(
    const float4* __restrict__ in, float4* __restrict__ out) {
    // XCD-contiguous swizzle: gridDim.x = 4096, divisible by 8 -> bijective.
    int bid  = (int)blockIdx.x;
    int sbid = (bid & 7) * ((int)gridDim.x >> 3) + (bid >> 3);
    int t    = sbid * 256 + (int)threadIdx.x;

    int cq = t & 7;          // channel quad 0..7
    int kp = (t >> 3) & 31;  // x-pair
    int j2 = (t >> 8) & 31;  // y-pair
    int i2 = (t >> 13) & 31; // z-pair
    int b  = t >> 18;        // batch

    // output coords: (x1,x2), (y1,y2), (z1,z2); input stencil corner at (x0,y0,z0)
    int x1 = kp << 1, x2 = x1 + 1, x0 = (x1 > 0) ? x1 - 1 : 0;
    int y1 = j2 << 1, y2 = y1 + 1, y0 = (y1 > 0) ? y1 - 1 : 0;
    int z1 = i2 << 1, z2 = z1 + 1, z0 = (z1 > 0) ? z1 - 1 : 0;

    const float s = 62.0f / 63.0f;
    // f(m) = frac(m*s); out[m] = in[m-1]*(1-f) + in[m]*f  (m=0: f=0, clamp benign)
    float tx0 = (float)x1 * s; float fx0 = tx0 - (float)(int)tx0; float gx0 = 1.0f - fx0;
    float tx1 = (float)x2 * s; float fx1 = tx1 - (float)(int)tx1; float gx1 = 1.0f - fx1;
    float ty0 = (float)y1 * s; float fy0 = ty0 - (float)(int)ty0; float gy0 = 1.0f - fy0;
    float ty1 = (float)y2 * s; float fy1 = ty1 - (float)(int)ty1; float gy1 = 1.0f - fy1;
    float tz0 = (float)z1 * s; float fz0 = tz0 - (float)(int)tz0; float gz0 = 1.0f - fz0;
    float tz1 = (float)z2 * s; float fz1 = tz1 - (float)(int)tz1; float gz1 = 1.0f - fz1;

    // quad index = (((b*64+z)*64+y)*64+x)*8 + cq
    int bb  = b << 21;
    int za  = bb + (z0 << 15), zbp = bb + (z1 << 15), zc = bb + (z2 << 15);
    int ry0 = y0 << 9, ry1 = y1 << 9, ry2 = y2 << 9;
    int xo0 = (x0 << 3) + cq, xo1 = (x1 << 3) + cq, xo2 = (x2 << 3) + cq;

    // ---- all 27 loads up front, distinct registers (MLP) ----
#define LOADP(N, ZO)                                                            \
    float4 N##00 = in[(ZO) + ry0 + xo0];                                        \
    float4 N##01 = in[(ZO) + ry0 + xo1];                                        \
    float4 N##02 = in[(ZO) + ry0 + xo2];                                        \
    float4 N##10 = in[(ZO) + ry1 + xo0];                                        \
    float4 N##11 = in[(ZO) + ry1 + xo1];                                        \
    float4 N##12 = in[(ZO) + ry1 + xo2];                                        \
    float4 N##20 = in[(ZO) + ry2 + xo0];                                        \
    float4 N##21 = in[(ZO) + ry2 + xo1];                                        \
    float4 N##22 = in[(ZO) + ry2 + xo2];

    LOADP(A, za)
    LOADP(B, zbp)
    LOADP(C, zc)
#undef LOADP

    // ---- x-blend: 3 planes x 3 rows x 2 x-outputs ----
#define XB(N)                                                                   \
    float4 N##x00 = f4lerp(N##00, gx0, N##01, fx0);                             \
    float4 N##x01 = f4lerp(N##01, gx1, N##02, fx1);                             \
    float4 N##x10 = f4lerp(N##10, gx0, N##11, fx0);                             \
    float4 N##x11 = f4lerp(N##11, gx1, N##12, fx1);                             \
    float4 N##x20 = f4lerp(N##20, gx0, N##21, fx0);                             \
    float4 N##x21 = f4lerp(N##21, gx1, N##22, fx1);
    XB(A) XB(B) XB(C)
#undef XB

    // ---- y-blend: 3 planes x 2 y-outputs x 2 x-outputs ----
#define YB(N)                                                                   \
    float4 N##y00 = f4lerp(N##x00, gy0, N##x10, fy0);                           \
    float4 N##y01 = f4lerp(N##x01, gy0, N##x11, fy0);                           \
    float4 N##y10 = f4lerp(N##x10, gy1, N##x20, fy1);                           \
    float4 N##y11 = f4lerp(N##x11, gy1, N##x21, fy1);
    YB(A) YB(B) YB(C)
#undef YB

    // ---- z-blend: 8 outputs ----
    float4 o000 = f4lerp(Ay00, gz0, By00, fz0);
    float4 o001 = f4lerp(Ay01, gz0, By01, fz0);
    float4 o010 = f4lerp(Ay10, gz0, By10, fz0);
    float4 o011 = f4lerp(Ay11, gz0, By11, fz0);
    float4 o100 = f4lerp(By00, gz1, Cy00, fz1);
    float4 o101 = f4lerp(By01, gz1, Cy01, fz1);
    float4 o110 = f4lerp(By10, gz1, Cy10, fz1);
    float4 o111 = f4lerp(By11, gz1, Cy11, fz1);

    int base = bb + (y1 << 9) + (x1 << 3) + cq;
    int zb1  = z1 << 15, zb2 = z2 << 15;
    nt_store(o000, &out[base + zb1]);
    nt_store(o001, &out[base + zb1 + 8]);
    nt_store(o010, &out[base + zb1 + 512]);
    nt_store(o011, &out[base + zb1 + 520]);
    nt_store(o100, &out[base + zb2]);
    nt_store(o101, &out[base + zb2 + 8]);
    nt_store(o110, &out[base + zb2 + 512]);
    nt_store(o111, &out[base + zb2 + 520]);
}

extern "C" void kernel_launch(void* const* d_in, const int* in_sizes, int n_in,
                              void* d_out, int out_size, void* d_ws, size_t ws_size,
                              hipStream_t stream) {
    const float4* in = (const float4*)d_in[0];
    float4* out = (float4*)d_out;

    // threads = 4 batches * 32^3 pair-voxels * 8 quads = 2^20
    const int total = 4 * 32 * 32 * 32 * C4;
    const int block = 256;
    const int grid  = total / block;  // 4096

    trilerp_kernel<<<grid, block, 0, stream>>>(in, out);
}